// Round 7
// baseline (136.126 us; speedup 1.0000x reference)
//
#include <hip/hip_runtime.h>
#include <hip/hip_bf16.h>

typedef __hip_bfloat16 bf16;
typedef __attribute__((ext_vector_type(8))) short short8;   // 8 bf16 = K=32 MFMA A/B frag
typedef __attribute__((ext_vector_type(4))) short short4v;  // 4 bf16
typedef __attribute__((ext_vector_type(4))) float f32x4;    // MFMA C/D frag
typedef __attribute__((ext_vector_type(4))) unsigned uint4v;
typedef __attribute__((ext_vector_type(2))) unsigned uint2v;

#define NB 128   // B*TO
#define CC 64    // channels
#define TT 1024  // time

#if __has_builtin(__builtin_amdgcn_exp2f)
#define EXP2(x) __builtin_amdgcn_exp2f(x)
#else
#define EXP2(x) exp2f(x)
#endif

// ---- cheap bf16 conversion: round-half-up via +0x8000, pack 2 per v_perm ---
__device__ __forceinline__ unsigned rnd_u(float f) {
  return __builtin_bit_cast(unsigned, f) + 0x8000u;
}
__device__ __forceinline__ unsigned packbf2(unsigned uhi, unsigned ulo) {
  return __builtin_amdgcn_perm(uhi, ulo, 0x07060302);
}
__device__ __forceinline__ short4v pack4(float a, float b, float c, float d) {
  unsigned pd[2] = { packbf2(rnd_u(b), rnd_u(a)), packbf2(rnd_u(d), rnd_u(c)) };
  return *(const short4v*)pd;
}

__device__ __forceinline__ f32x4 mfma32(short8 a, short8 b, f32x4 c) {
  return __builtin_amdgcn_mfma_f32_16x16x32_bf16(a, b, c, 0, 0, 0);
}

// ---------------------------------------------------------------------------
// Kernel 0: weight-product precompute (r16).
//   M[a][b]  = (sum_c Wk[c][a]*Wq[c][b]) * scale * log2(e)   (row-major, 64x64)
//   W2perm   = Wo*Wv stored in the attn-epilogue PERMUTED layout:
//              position o*64+u*32+q4*8+j holds W2[o][(2u+(j>>2))*16+q4*4+(j&3)],
//              W2[o][a] = sum_c Wo[o][c]*Wv[c][a].
// Algebra: S^T = x_s^T (Wk^T Wq) x_q ; out = (Wo Wv)(x_s P)/l + x_q.
// ---------------------------------------------------------------------------
__global__ __launch_bounds__(256) void wprep(
    const float* __restrict__ Wq, const float* __restrict__ Wk,
    const float* __restrict__ Wv, const float* __restrict__ Wo,
    const float* __restrict__ scale_p, bf16* __restrict__ wmw)
{
  const int g = blockIdx.x * 256 + threadIdx.x;
  float acc = 0.f;
  if (g < 4096) {
    const int a = g >> 6, b = g & 63;
    #pragma unroll 8
    for (int c = 0; c < 64; c++) acc += Wk[c * 64 + a] * Wq[c * 64 + b];
    acc *= (*scale_p) * 1.44269504089f;
    wmw[g] = __float2bfloat16(acc);
  } else {
    const int ii = g - 4096;
    const int o = ii >> 6, cp = ii & 63;          // cp = permuted position
    const int u = cp >> 5, q4 = (cp >> 3) & 3, j = cp & 7;
    const int a = (2 * u + (j >> 2)) * 16 + q4 * 4 + (j & 3);
    #pragma unroll 8
    for (int c = 0; c < 64; c++) acc += Wo[o * 64 + c] * Wv[c * 64 + a];
    wmw[g] = __float2bfloat16(acc);
  }
}

// ---------------------------------------------------------------------------
// Kernel 1: FULLY FUSED attention (r17 inner loop, r18 geometry).
// r18: QTILE 128 -> 256 with 512-thread 8-wave blocks, grid 512.
//  * per-CU waves UNCHANGED (2 blocks x 8 waves = 16 — r14's regression came
//    from dropping to 8 waves/CU; we avoid that).
//  * each x[n] s-tile is staged by 4 blocks instead of 8 -> staging
//    global-load issue, pack VALU and LDS writes per CU all HALVE.
//  * staging remap for 512 threads: thread = 4 c-rows x 2 s
//    (ts=tid&31 -> s=2ts+e; cg=tid>>5 -> c=cg*4+j). Global: 4x float2
//    (256B segments). ks[s][c]: 2x b64 at (2ts+e)*72+cg*4 (same cycle
//    count as r17). vs[c][s']: 4x b32, 32 banks x 2 lanes = free.
//  * inner loop per wave (phase1 S^T+exp2, lacc ones-MFMA, phase2 PV,
//    K=32 everywhere) is BIT-IDENTICAL to r17.
// obuf 64x260 fp32 = 66560 B (hardware-proven size in r14 run); 2
// blocks/CU = 133 KB < 160 KB.
// Layouts (m89/m120-verified): A[m=lane&15][k=quad*8+j];
// B[k=quad*8+j][n=lane&15]; C/D row=quad*4+reg, col=lane&15.
// ---------------------------------------------------------------------------
__global__ __launch_bounds__(512, 4) void attn_fused(
    const bf16* __restrict__ wm, const bf16* __restrict__ w2,
    const float* __restrict__ x, float* __restrict__ out)
{
  __shared__ float obuf[64 * 260];          // 66560 B; staging aliases front
  short* xq = (short*)obuf;                 // prologue [256 t][72]   (36864 B)
  short* ks = (short*)obuf;                 // loop: K-side [s][c]    (9216 B)
  short* vs = ks + 64 * 72;                 // loop: Z-side [c][s']   (9216 B)

  const int bid = blockIdx.x;
  const int n   = bid & 127;        // bid%8 == n%8 -> same-n blocks share an XCD
  const int qt0 = (bid >> 7) * 256;
  const int tid = threadIdx.x;
  const int w   = tid >> 6;         // 0..7
  const int il  = tid & 15;
  const int q4  = (tid & 63) >> 4;
  const size_t nbase = (size_t)n * (CC * TT);

  // staging thread coords (r18): 4 c-rows x 2 s-cols per thread
  const int ts  = tid & 31;         // s-pair index: s = 2ts + e
  const int cg  = tid >> 5;         // c-group 0..15: c = cg*4 + j
  const int krow = ts * 2;
  const int sp0 = ((ts >> 1) & 3) * 16 + (ts >> 3) * 4 + (ts & 1) * 2;  // perm'd s

  // ================= prologue: Y = M x_q (256 t) ===========================
  #pragma unroll
  for (int g = 0; g < 4; g++) {
    float2 xr[4];
    #pragma unroll
    for (int j = 0; j < 4; j++)
      xr[j] = *(const float2*)&x[nbase + (size_t)(cg * 4 + j) * TT + qt0 + g * 64 + ts * 2];
    #pragma unroll
    for (int e = 0; e < 2; e++) {
      unsigned kd[2];
      #pragma unroll
      for (int d = 0; d < 2; d++) {
        float lo = e ? xr[2 * d].y     : xr[2 * d].x;
        float hi = e ? xr[2 * d + 1].y : xr[2 * d + 1].x;
        kd[d] = packbf2(rnd_u(hi), rnd_u(lo));
      }
      *(uint2v*)&xq[(g * 64 + krow + e) * 72 + cg * 4] = *(const uint2v*)kd;
    }
  }
  __syncthreads();

  // Y-mfma: D[a][t] for this wave's 32 t-cols (t = w*32 + mt*16 + il)
  f32x4 yacc[4][2];
  #pragma unroll
  for (int at = 0; at < 4; at++)
    #pragma unroll
    for (int mt = 0; mt < 2; mt++) yacc[at][mt] = (f32x4){0.f, 0.f, 0.f, 0.f};
  #pragma unroll
  for (int kk = 0; kk < 2; kk++) {
    short8 xb0 = *(const short8*)&xq[(w * 32 + il) * 72 + kk * 32 + q4 * 8];
    short8 xb1 = *(const short8*)&xq[(w * 32 + 16 + il) * 72 + kk * 32 + q4 * 8];
    #pragma unroll
    for (int at = 0; at < 4; at++) {
      short8 ma = *(const short8*)&wm[(at * 16 + il) * 64 + kk * 32 + q4 * 8];
      yacc[at][0] = mfma32(ma, xb0, yacc[at][0]);
      yacc[at][1] = mfma32(ma, xb1, yacc[at][1]);
    }
  }
  __syncthreads();          // all xq reads done before overwrite
  // D[a = at*16+q4*4+r][t] -> LDS [t][a]; contiguous in r -> short4v
  #pragma unroll
  for (int at = 0; at < 4; at++)
    #pragma unroll
    for (int mt = 0; mt < 2; mt++)
      *(short4v*)&xq[(w * 32 + mt * 16 + il) * 72 + at * 16 + q4 * 4] =
          pack4(yacc[at][mt][0], yacc[at][mt][1], yacc[at][mt][2], yacc[at][mt][3]);
  __syncthreads();
  // Y B-frags: B[k=a][n=t]
  short8 yb[2][2];
  #pragma unroll
  for (int mt = 0; mt < 2; mt++)
    #pragma unroll
    for (int kk = 0; kk < 2; kk++)
      yb[mt][kk] = *(const short8*)&xq[(w * 32 + mt * 16 + il) * 72 + kk * 32 + q4 * 8];

  const short8 ones8 = { 0x3F80, 0x3F80, 0x3F80, 0x3F80,
                         0x3F80, 0x3F80, 0x3F80, 0x3F80 };  // bf16 1.0 x8

  f32x4 oaccT[2][4];                // [mt][ct]: Z[a][t], a=ct*16+q4*4+r, t=mt*16+il
  f32x4 lacc[2];                    // denominator via ones-MFMA
  #pragma unroll
  for (int mt = 0; mt < 2; mt++) {
    lacc[mt] = (f32x4){0.f, 0.f, 0.f, 0.f};
    #pragma unroll
    for (int ct = 0; ct < 4; ct++) oaccT[mt][ct] = (f32x4){0.f, 0.f, 0.f, 0.f};
  }

  // prefetch s-tile 0 (fp32): 4 c-rows x 2 s
  float2 xr[4];
  #pragma unroll
  for (int j = 0; j < 4; j++)
    xr[j] = *(const float2*)&x[nbase + (size_t)(cg * 4 + j) * TT + ts * 2];

  #pragma unroll 1
  for (int st = 0; st < 16; st++) {
    __syncthreads();                 // prev-iter compute reads done (iter 0: yb reads)
    // ks[s][c]: 2x b64
    #pragma unroll
    for (int e = 0; e < 2; e++) {
      unsigned kd[2];
      #pragma unroll
      for (int d = 0; d < 2; d++) {
        float lo = e ? xr[2 * d].y     : xr[2 * d].x;
        float hi = e ? xr[2 * d + 1].y : xr[2 * d + 1].x;
        kd[d] = packbf2(rnd_u(hi), rnd_u(lo));
      }
      *(uint2v*)&ks[(krow + e) * 72 + cg * 4] = *(const uint2v*)kd;
    }
    // vs[c][s']: 4x b32, 2 lanes/bank (free)
    #pragma unroll
    for (int j = 0; j < 4; j++)
      *(unsigned*)&vs[(cg * 4 + j) * 72 + sp0] = packbf2(rnd_u(xr[j].y), rnd_u(xr[j].x));
    if (st < 15) {                   // prefetch st+1: in flight across barrier
      const int s1 = (st + 1) * 64;
      #pragma unroll
      for (int j = 0; j < 4; j++)
        xr[j] = *(const float2*)&x[nbase + (size_t)(cg * 4 + j) * TT + s1 + ts * 2];
    }
    __syncthreads();                 // ks/vs visible

    // ---- phase 1: S^T = x_s^T Y, exp2 -> P packed into K=32 B-frag halves
    uint4v pq[2][2];
    #pragma unroll
    for (int st2 = 0; st2 < 4; st2++) {
      short8 ka0 = *(const short8*)&ks[(st2 * 16 + il) * 72 + q4 * 8];
      short8 ka1 = *(const short8*)&ks[(st2 * 16 + il) * 72 + 32 + q4 * 8];
      #pragma unroll
      for (int mt = 0; mt < 2; mt++) {
        f32x4 sT = (f32x4){0.f, 0.f, 0.f, 0.f};
        sT = mfma32(ka0, yb[mt][0], sT);
        sT = mfma32(ka1, yb[mt][1], sT);
        float p0 = EXP2(sT[0]), p1 = EXP2(sT[1]), p2 = EXP2(sT[2]), p3 = EXP2(sT[3]);
        pq[mt][st2 >> 1][(st2 & 1) * 2]     = packbf2(rnd_u(p1), rnd_u(p0));
        pq[mt][st2 >> 1][(st2 & 1) * 2 + 1] = packbf2(rnd_u(p3), rnd_u(p2));
      }
    }
    short8 pb[2][2];
    #pragma unroll
    for (int mt = 0; mt < 2; mt++)
      #pragma unroll
      for (int u = 0; u < 2; u++) {
        pb[mt][u] = __builtin_bit_cast(short8, pq[mt][u]);
        lacc[mt] = mfma32(ones8, pb[mt][u], lacc[mt]);   // row-sum, K=32
      }

    // ---- phase 2: Z += x_s P at K=32; permuted vs: h0/h1 are strip-pair A-frags
    #pragma unroll
    for (int ct = 0; ct < 4; ct++) {
      short8 h0 = *(const short8*)&vs[(ct * 16 + il) * 72 + q4 * 16];
      short8 h1 = *(const short8*)&vs[(ct * 16 + il) * 72 + q4 * 16 + 8];
      #pragma unroll
      for (int mt = 0; mt < 2; mt++) {
        oaccT[mt][ct] = mfma32(h0, pb[mt][0], oaccT[mt][ct]);
        oaccT[mt][ct] = mfma32(h1, pb[mt][1], oaccT[mt][ct]);
      }
    }
  }

  // ================= epilogue ==============================================
  float linv[2];
  #pragma unroll
  for (int mt = 0; mt < 2; mt++) linv[mt] = 1.f / lacc[mt][0];

  // Z regs -> bf16 K=32 B-frags: concat of ct-pair (2u, 2u+1)
  uint4v obq[2][2];
  #pragma unroll
  for (int mt = 0; mt < 2; mt++)
    #pragma unroll
    for (int ct = 0; ct < 4; ct++) {
      float a = oaccT[mt][ct][0] * linv[mt], b = oaccT[mt][ct][1] * linv[mt];
      float c = oaccT[mt][ct][2] * linv[mt], d = oaccT[mt][ct][3] * linv[mt];
      obq[mt][ct >> 1][(ct & 1) * 2]     = packbf2(rnd_u(b), rnd_u(a));
      obq[mt][ct >> 1][(ct & 1) * 2 + 1] = packbf2(rnd_u(d), rnd_u(c));
    }
  short8 ob8[2][2];
  #pragma unroll
  for (int mt = 0; mt < 2; mt++)
    #pragma unroll
    for (int u = 0; u < 2; u++)
      ob8[mt][u] = __builtin_bit_cast(short8, obq[mt][u]);

  __syncthreads();   // all loop reads of ks/vs done before obuf overwrites them

  // res[o][t] = W2(A) x Z(B) at K=32 -> obuf[o][t_local] (fp32, stride 260)
  #pragma unroll
  for (int ot = 0; ot < 4; ot++) {
    short8 wa0 = *(const short8*)&w2[(ot * 16 + il) * 64 + q4 * 8];
    short8 wa1 = *(const short8*)&w2[(ot * 16 + il) * 64 + 32 + q4 * 8];
    #pragma unroll
    for (int mt = 0; mt < 2; mt++) {
      f32x4 res = (f32x4){0.f, 0.f, 0.f, 0.f};
      res = mfma32(wa0, ob8[mt][0], res);
      res = mfma32(wa1, ob8[mt][1], res);
      #pragma unroll
      for (int r = 0; r < 4; r++)
        obuf[(ot * 16 + q4 * 4 + r) * 260 + w * 32 + mt * 16 + il] = res[r];
    }
  }
  __syncthreads();

  // coalesced store + residual: full 128B lines (8-lane groups x float4)
  const int orow = tid >> 3;          // 0..63
  const int ocb  = (tid & 7) * 4;     // col base
  #pragma unroll
  for (int k = 0; k < 8; k++) {
    const int col = ocb + k * 32;
    float4 val = *(const float4*)&obuf[orow * 260 + col];
    const size_t idx = nbase + (size_t)orow * TT + qt0 + col;
    float4 xv = *(const float4*)&x[idx];
    val.x += xv.x; val.y += xv.y; val.z += xv.z; val.w += xv.w;
    *(float4*)&out[idx] = val;
  }
}

// ---------------------------------------------------------------------------
extern "C" void kernel_launch(void* const* d_in, const int* in_sizes, int n_in,
                              void* d_out, int out_size, void* d_ws, size_t ws_size,
                              hipStream_t stream) {
  const float* x     = (const float*)d_in[0];
  const float* Wq    = (const float*)d_in[1];
  const float* Wk    = (const float*)d_in[2];
  const float* Wv    = (const float*)d_in[3];
  const float* Wo    = (const float*)d_in[4];
  const float* scale = (const float*)d_in[5];
  float* out = (float*)d_out;

  bf16* wmw = (bf16*)d_ws;          // [0..4095] = M, [4096..8191] = W2 (permuted)

  wprep<<<32, 256, 0, stream>>>(Wq, Wk, Wv, Wo, scale, wmw);
  attn_fused<<<512, 512, 0, stream>>>(wmw, wmw + 4096, x, out);
}

// Round 8
// 134.047 us; speedup vs baseline: 1.0155x; 1.0155x over previous
//
#include <hip/hip_runtime.h>
#include <hip/hip_bf16.h>

typedef __hip_bfloat16 bf16;
typedef __attribute__((ext_vector_type(8))) short short8;   // 8 bf16 = K=32 MFMA A/B frag
typedef __attribute__((ext_vector_type(4))) short short4v;  // 4 bf16
typedef __attribute__((ext_vector_type(4))) float f32x4;    // MFMA C/D frag
typedef __attribute__((ext_vector_type(4))) unsigned uint4v;

#define NB 128   // B*TO
#define CC 64    // channels
#define TT 1024  // time

#if __has_builtin(__builtin_amdgcn_exp2f)
#define EXP2(x) __builtin_amdgcn_exp2f(x)
#else
#define EXP2(x) exp2f(x)
#endif

// ---- cheap bf16 conversion: round-half-up via +0x8000, pack 2 per v_perm ---
__device__ __forceinline__ unsigned rnd_u(float f) {
  return __builtin_bit_cast(unsigned, f) + 0x8000u;
}
__device__ __forceinline__ unsigned packbf2(unsigned uhi, unsigned ulo) {
  return __builtin_amdgcn_perm(uhi, ulo, 0x07060302);
}
__device__ __forceinline__ short4v pack4(float a, float b, float c, float d) {
  unsigned pd[2] = { packbf2(rnd_u(b), rnd_u(a)), packbf2(rnd_u(d), rnd_u(c)) };
  return *(const short4v*)pd;
}

__device__ __forceinline__ f32x4 mfma32(short8 a, short8 b, f32x4 c) {
  return __builtin_amdgcn_mfma_f32_16x16x32_bf16(a, b, c, 0, 0, 0);
}

// ---------------------------------------------------------------------------
// Kernel 0: weight-product precompute (r16).
//   M[a][b]  = (sum_c Wk[c][a]*Wq[c][b]) * scale * log2(e)   (row-major, 64x64)
//   W2perm   = Wo*Wv stored in the attn-epilogue PERMUTED layout:
//              position o*64+u*32+q4*8+j holds W2[o][(2u+(j>>2))*16+q4*4+(j&3)],
//              W2[o][a] = sum_c Wo[o][c]*Wv[c][a].
// Algebra: S^T = x_s^T (Wk^T Wq) x_q ; out = (Wo Wv)(x_s P)/l + x_q.
// ---------------------------------------------------------------------------
__global__ __launch_bounds__(256) void wprep(
    const float* __restrict__ Wq, const float* __restrict__ Wk,
    const float* __restrict__ Wv, const float* __restrict__ Wo,
    const float* __restrict__ scale_p, bf16* __restrict__ wmw)
{
  const int g = blockIdx.x * 256 + threadIdx.x;
  float acc = 0.f;
  if (g < 4096) {
    const int a = g >> 6, b = g & 63;
    #pragma unroll 8
    for (int c = 0; c < 64; c++) acc += Wk[c * 64 + a] * Wq[c * 64 + b];
    acc *= (*scale_p) * 1.44269504089f;
    wmw[g] = __float2bfloat16(acc);
  } else {
    const int ii = g - 4096;
    const int o = ii >> 6, cp = ii & 63;          // cp = permuted position
    const int u = cp >> 5, q4 = (cp >> 3) & 3, j = cp & 7;
    const int a = (2 * u + (j >> 2)) * 16 + q4 * 4 + (j & 3);
    #pragma unroll 8
    for (int c = 0; c < 64; c++) acc += Wo[o * 64 + c] * Wv[c * 64 + a];
    wmw[g] = __float2bfloat16(acc);
  }
}

// ---------------------------------------------------------------------------
// Kernel 1: FULLY FUSED attention (r17 geometry EXACTLY — r18's 512-thread
// variant re-introduced an 8-way ks-write conflict (6.68M vs 5.90M) with
// flat dur; reverted).
// r19 change: s_setprio wave-priority shaping (T5, m191-proven +4-7% on
// attn-class kernels with independent blocks). Staging + global prefetch
// run at prio 0; the MFMA-dense region (phase1 S^T+exp2, lacc, phase2 PV)
// runs at prio 1, so co-resident blocks' staging waves don't starve the
// matrix pipe of issue slots.
// Staging (r17, conflict-minimal): thread = 8 c-rows x 2 s (ts=tid&31,
// cg=tid>>5): global 8x float2; ks[s][c] 2x b128 (8 disjoint 4-bank groups);
// vs[c][s'] 8x b32 (32 banks x 2 lanes = free).
// Layouts (m89/m120-verified): A[m=lane&15][k=quad*8+j];
// B[k=quad*8+j][n=lane&15]; C/D row=quad*4+reg, col=lane&15.
// ---------------------------------------------------------------------------
__global__ __launch_bounds__(256, 4) void attn_fused(
    const bf16* __restrict__ wm, const bf16* __restrict__ w2,
    const float* __restrict__ x, float* __restrict__ out)
{
  __shared__ float obuf[64 * 132];          // 33792 B; staging aliases front
  short* xq = (short*)obuf;                 // prologue [128 t][72]   (18432 B)
  short* ks = (short*)obuf;                 // loop: K-side [s][c]    (9216 B)
  short* vs = ks + 64 * 72;                 // loop: Z-side [c][s']   (9216 B)

  const int bid = blockIdx.x;
  const int n   = bid & 127;        // bid%8 == n%8 -> same-n blocks share an XCD
  const int qt0 = (bid >> 7) * 128;
  const int tid = threadIdx.x;
  const int w   = tid >> 6;
  const int il  = tid & 15;
  const int q4  = (tid & 63) >> 4;
  const size_t nbase = (size_t)n * (CC * TT);

  // staging thread coords (r17): 8 c-rows x 2 s-cols per thread
  const int ts  = tid & 31;         // s-pair index: s = ts*2 + e
  const int cg  = tid >> 5;         // c-group: c = cg*8 + j
  const int krow = ts * 2;
  const int sp0 = ((ts >> 1) & 3) * 16 + (ts >> 3) * 4 + (ts & 1) * 2;  // perm'd s

  // ================= prologue: Y = M x_q ===================================
  #pragma unroll
  for (int half = 0; half < 2; half++) {
    float2 xr[8];
    #pragma unroll
    for (int j = 0; j < 8; j++)
      xr[j] = *(const float2*)&x[nbase + (size_t)(cg * 8 + j) * TT + qt0 + half * 64 + ts * 2];
    #pragma unroll
    for (int e = 0; e < 2; e++) {
      unsigned kd[4];
      #pragma unroll
      for (int d = 0; d < 4; d++) {
        float lo = e ? xr[2 * d].y     : xr[2 * d].x;
        float hi = e ? xr[2 * d + 1].y : xr[2 * d + 1].x;
        kd[d] = packbf2(rnd_u(hi), rnd_u(lo));
      }
      *(uint4v*)&xq[(half * 64 + krow + e) * 72 + cg * 8] = *(const uint4v*)kd;
    }
  }
  __syncthreads();

  // Y-mfma: D[a][t] for this wave's 32 t-cols (t = w*32 + mt*16 + il)
  f32x4 yacc[4][2];
  #pragma unroll
  for (int at = 0; at < 4; at++)
    #pragma unroll
    for (int mt = 0; mt < 2; mt++) yacc[at][mt] = (f32x4){0.f, 0.f, 0.f, 0.f};
  #pragma unroll
  for (int kk = 0; kk < 2; kk++) {
    short8 xb0 = *(const short8*)&xq[(w * 32 + il) * 72 + kk * 32 + q4 * 8];
    short8 xb1 = *(const short8*)&xq[(w * 32 + 16 + il) * 72 + kk * 32 + q4 * 8];
    #pragma unroll
    for (int at = 0; at < 4; at++) {
      short8 ma = *(const short8*)&wm[(at * 16 + il) * 64 + kk * 32 + q4 * 8];
      yacc[at][0] = mfma32(ma, xb0, yacc[at][0]);
      yacc[at][1] = mfma32(ma, xb1, yacc[at][1]);
    }
  }
  __syncthreads();          // all xq reads done before overwrite
  // D[a = at*16+q4*4+r][t] -> LDS [t][a]; contiguous in r -> short4v
  #pragma unroll
  for (int at = 0; at < 4; at++)
    #pragma unroll
    for (int mt = 0; mt < 2; mt++)
      *(short4v*)&xq[(w * 32 + mt * 16 + il) * 72 + at * 16 + q4 * 4] =
          pack4(yacc[at][mt][0], yacc[at][mt][1], yacc[at][mt][2], yacc[at][mt][3]);
  __syncthreads();
  // Y B-frags: B[k=a][n=t]
  short8 yb[2][2];
  #pragma unroll
  for (int mt = 0; mt < 2; mt++)
    #pragma unroll
    for (int kk = 0; kk < 2; kk++)
      yb[mt][kk] = *(const short8*)&xq[(w * 32 + mt * 16 + il) * 72 + kk * 32 + q4 * 8];

  const short8 ones8 = { 0x3F80, 0x3F80, 0x3F80, 0x3F80,
                         0x3F80, 0x3F80, 0x3F80, 0x3F80 };  // bf16 1.0 x8

  f32x4 oaccT[2][4];                // [mt][ct]: Z[a][t], a=ct*16+q4*4+r, t=mt*16+il
  f32x4 lacc[2];                    // denominator via ones-MFMA
  #pragma unroll
  for (int mt = 0; mt < 2; mt++) {
    lacc[mt] = (f32x4){0.f, 0.f, 0.f, 0.f};
    #pragma unroll
    for (int ct = 0; ct < 4; ct++) oaccT[mt][ct] = (f32x4){0.f, 0.f, 0.f, 0.f};
  }

  // prefetch s-tile 0 (fp32): 8 rows x 2 cols
  float2 xr[8];
  #pragma unroll
  for (int j = 0; j < 8; j++)
    xr[j] = *(const float2*)&x[nbase + (size_t)(cg * 8 + j) * TT + ts * 2];

  #pragma unroll 1
  for (int st = 0; st < 16; st++) {
    __syncthreads();                 // prev-iter compute reads done (iter 0: yb reads)
    // ---- staging at prio 0 ----
    // ks[s][c]: 2x b128, conflict-free start banks
    #pragma unroll
    for (int e = 0; e < 2; e++) {
      unsigned kd[4];
      #pragma unroll
      for (int d = 0; d < 4; d++) {
        float lo = e ? xr[2 * d].y     : xr[2 * d].x;
        float hi = e ? xr[2 * d + 1].y : xr[2 * d + 1].x;
        kd[d] = packbf2(rnd_u(hi), rnd_u(lo));
      }
      *(uint4v*)&ks[(krow + e) * 72 + cg * 8] = *(const uint4v*)kd;
    }
    // vs[c][s']: 8x b32, 2 lanes/bank (free)
    #pragma unroll
    for (int j = 0; j < 8; j++)
      *(unsigned*)&vs[(cg * 8 + j) * 72 + sp0] = packbf2(rnd_u(xr[j].y), rnd_u(xr[j].x));
    if (st < 15) {                   // prefetch st+1: in flight across barrier
      const int s1 = (st + 1) * 64;
      #pragma unroll
      for (int j = 0; j < 8; j++)
        xr[j] = *(const float2*)&x[nbase + (size_t)(cg * 8 + j) * TT + s1 + ts * 2];
    }
    __syncthreads();                 // ks/vs visible

    // ---- compute at prio 1: keep the matrix pipe fed while other blocks
    // stage (T5, m191) ----
    __builtin_amdgcn_s_setprio(1);

    // ---- phase 1: S^T = x_s^T Y, exp2 -> P packed into K=32 B-frag halves
    uint4v pq[2][2];
    #pragma unroll
    for (int st2 = 0; st2 < 4; st2++) {
      short8 ka0 = *(const short8*)&ks[(st2 * 16 + il) * 72 + q4 * 8];
      short8 ka1 = *(const short8*)&ks[(st2 * 16 + il) * 72 + 32 + q4 * 8];
      #pragma unroll
      for (int mt = 0; mt < 2; mt++) {
        f32x4 sT = (f32x4){0.f, 0.f, 0.f, 0.f};
        sT = mfma32(ka0, yb[mt][0], sT);
        sT = mfma32(ka1, yb[mt][1], sT);
        float p0 = EXP2(sT[0]), p1 = EXP2(sT[1]), p2 = EXP2(sT[2]), p3 = EXP2(sT[3]);
        pq[mt][st2 >> 1][(st2 & 1) * 2]     = packbf2(rnd_u(p1), rnd_u(p0));
        pq[mt][st2 >> 1][(st2 & 1) * 2 + 1] = packbf2(rnd_u(p3), rnd_u(p2));
      }
    }
    short8 pb[2][2];
    #pragma unroll
    for (int mt = 0; mt < 2; mt++)
      #pragma unroll
      for (int u = 0; u < 2; u++) {
        pb[mt][u] = __builtin_bit_cast(short8, pq[mt][u]);
        lacc[mt] = mfma32(ones8, pb[mt][u], lacc[mt]);   // row-sum, K=32
      }

    // ---- phase 2: Z += x_s P at K=32; permuted vs: h0/h1 are strip-pair A-frags
    #pragma unroll
    for (int ct = 0; ct < 4; ct++) {
      short8 h0 = *(const short8*)&vs[(ct * 16 + il) * 72 + q4 * 16];
      short8 h1 = *(const short8*)&vs[(ct * 16 + il) * 72 + q4 * 16 + 8];
      #pragma unroll
      for (int mt = 0; mt < 2; mt++) {
        oaccT[mt][ct] = mfma32(h0, pb[mt][0], oaccT[mt][ct]);
        oaccT[mt][ct] = mfma32(h1, pb[mt][1], oaccT[mt][ct]);
      }
    }

    __builtin_amdgcn_s_setprio(0);
  }

  // ================= epilogue ==============================================
  float linv[2];
  #pragma unroll
  for (int mt = 0; mt < 2; mt++) linv[mt] = 1.f / lacc[mt][0];

  // Z regs -> bf16 K=32 B-frags: concat of ct-pair (2u, 2u+1)
  uint4v obq[2][2];
  #pragma unroll
  for (int mt = 0; mt < 2; mt++)
    #pragma unroll
    for (int ct = 0; ct < 4; ct++) {
      float a = oaccT[mt][ct][0] * linv[mt], b = oaccT[mt][ct][1] * linv[mt];
      float c = oaccT[mt][ct][2] * linv[mt], d = oaccT[mt][ct][3] * linv[mt];
      obq[mt][ct >> 1][(ct & 1) * 2]     = packbf2(rnd_u(b), rnd_u(a));
      obq[mt][ct >> 1][(ct & 1) * 2 + 1] = packbf2(rnd_u(d), rnd_u(c));
    }
  short8 ob8[2][2];
  #pragma unroll
  for (int mt = 0; mt < 2; mt++)
    #pragma unroll
    for (int u = 0; u < 2; u++)
      ob8[mt][u] = __builtin_bit_cast(short8, obq[mt][u]);

  __syncthreads();   // all loop reads of ks/vs done before obuf overwrites them

  // res[o][t] = W2(A) x Z(B) at K=32 -> obuf[o][t_local] (fp32, stride 132)
  #pragma unroll
  for (int ot = 0; ot < 4; ot++) {
    short8 wa0 = *(const short8*)&w2[(ot * 16 + il) * 64 + q4 * 8];
    short8 wa1 = *(const short8*)&w2[(ot * 16 + il) * 64 + 32 + q4 * 8];
    #pragma unroll
    for (int mt = 0; mt < 2; mt++) {
      f32x4 res = (f32x4){0.f, 0.f, 0.f, 0.f};
      res = mfma32(wa0, ob8[mt][0], res);
      res = mfma32(wa1, ob8[mt][1], res);
      #pragma unroll
      for (int r = 0; r < 4; r++)
        obuf[(ot * 16 + q4 * 4 + r) * 132 + w * 32 + mt * 16 + il] = res[r];
    }
  }
  __syncthreads();

  // coalesced store + residual: full 128B lines (8-lane groups x float4)
  const int orow = tid >> 3;          // 0..31
  const int ocb  = (tid & 7) * 4;     // col base
  #pragma unroll
  for (int half = 0; half < 2; half++) {
    const int row = orow + half * 32;
    #pragma unroll
    for (int k = 0; k < 4; k++) {
      const int col = ocb + k * 32;
      float4 val = *(const float4*)&obuf[row * 132 + col];
      const size_t idx = nbase + (size_t)row * TT + qt0 + col;
      float4 xv = *(const float4*)&x[idx];
      val.x += xv.x; val.y += xv.y; val.z += xv.z; val.w += xv.w;
      *(float4*)&out[idx] = val;
    }
  }
}

// ---------------------------------------------------------------------------
extern "C" void kernel_launch(void* const* d_in, const int* in_sizes, int n_in,
                              void* d_out, int out_size, void* d_ws, size_t ws_size,
                              hipStream_t stream) {
  const float* x     = (const float*)d_in[0];
  const float* Wq    = (const float*)d_in[1];
  const float* Wk    = (const float*)d_in[2];
  const float* Wv    = (const float*)d_in[3];
  const float* Wo    = (const float*)d_in[4];
  const float* scale = (const float*)d_in[5];
  float* out = (float*)d_out;

  bf16* wmw = (bf16*)d_ws;          // [0..4095] = M, [4096..8191] = W2 (permuted)

  wprep<<<32, 256, 0, stream>>>(Wq, Wk, Wv, Wo, scale, wmw);
  attn_fused<<<1024, 256, 0, stream>>>(wmw, wmw + 4096, x, out);
}